// Round 3
// baseline (150.174 us; speedup 1.0000x reference)
//
#include <hip/hip_runtime.h>
#include <hip/hip_bf16.h>
#include <math.h>

// Shapes: L=2048, B=32, E=1, S=4, D=8, N=8, P=720
#define LEN 2048
#define BDIM 32
#define PDIM 720

// Scratch in device globals (NOT d_ws) — avoids any assumption about ws_size.
// Every region is fully overwritten each call before any read (K1 writes all
// of g_Qv/g_Kv/g_u/g_hx/g_wsum; K2 writes all of g_hh), so no cross-call state.
__device__ float g_Qv[LEN * 8];
__device__ float g_Kv[LEN * 8];
__device__ float g_u[LEN];
__device__ float g_hx[LEN];
__device__ float g_wsum[LEN];
__device__ float g_hh[LEN];

__device__ __forceinline__ float sigmoidf_(float x) { return 1.0f / (1.0f + expf(-x)); }
__device__ __forceinline__ float siluf_(float x)    { return x / (1.0f + expf(-x)); }

// ---------------- K1: per-position precompute -------------------------------
// E=1 => layernorm output xn == norm_b[0] (constant c). Everything per-l:
//   conv[l] = c * sum_n g_n (1 - q_n^{l+1})/(1-q_n)     (closed-form of FFT conv)
//   mx = silu(conv + c*omega); base_j = mx*Wmx[j]+bmx[j]
//   u = sigmoid(base0); z=silu(base[1..4]); r=silu(base[5..12]); hx=base13
//   Qv[l] = [ (z*ag0+ab0)/L , rot_a(l) ];  Kv[l] = [ z*ag1+ab1 , rot_b(l) ]
//   wsum[l] = sum_d v_d * r_d * Wh_d   with v_d = silu(c*Wv_d + bv_d)
__global__ void k1_precompute(
    const float* __restrict__ norm_b,
    const float* __restrict__ ema_delta, const float* __restrict__ ema_alpha,
    const float* __restrict__ ema_beta,  const float* __restrict__ ema_gamma,
    const float* __restrict__ ema_omega,
    const float* __restrict__ Wv, const float* __restrict__ bv,
    const float* __restrict__ Wmx, const float* __restrict__ bmx,
    const float* __restrict__ Wh,
    const float* __restrict__ attn_gamma, const float* __restrict__ attn_beta,
    const float* __restrict__ rot_alpha,  const float* __restrict__ rot_beta)
{
    const int l = blockIdx.x * blockDim.x + threadIdx.x;
    if (l >= LEN) return;

    const float c = norm_b[0];
    const float res_e = c * ema_omega[0];

    // EMA long-conv, closed-form prefix sum of geometric kernels
    float conv = 0.0f;
    #pragma unroll
    for (int n = 0; n < 8; ++n) {
        float p  = sigmoidf_(ema_delta[n]);
        float s  = sigmoidf_(ema_alpha[n]);
        float om = p * s;            // = 1 - q, strictly in (0,1)
        float q  = 1.0f - om;
        float g  = p * ema_beta[n] * ema_gamma[n] * 0.35355339059327373f; // 1/sqrt(8)
        float qp = expf((float)(l + 1) * logf(q));   // q^(l+1)
        conv += g * (1.0f - qp) / om;
    }
    conv *= c;

    const float mx = siluf_(conv + res_e);

    const float u  = sigmoidf_(fmaf(mx, Wmx[0], bmx[0]));
    float z[4];
    #pragma unroll
    for (int s = 0; s < 4; ++s) z[s] = siluf_(fmaf(mx, Wmx[1 + s], bmx[1 + s]));
    float r[8];
    #pragma unroll
    for (int d = 0; d < 8; ++d) r[d] = siluf_(fmaf(mx, Wmx[5 + d], bmx[5 + d]));
    const float hx = fmaf(mx, Wmx[13], bmx[13]);

    float ws = 0.0f;
    #pragma unroll
    for (int d = 0; d < 8; ++d) {
        float v = siluf_(fmaf(c, Wv[d], bv[d]));
        ws += v * r[d] * Wh[d];
    }

    // rotary basis: half=2, freq = {1, exp(-log(1e4)/2)}
    const float f1 = expf(-logf(10000.0f) * 0.5f);
    const float c0 = cosf((float)l),      s0 = sinf((float)l);
    const float th = (float)l * f1;
    const float c1 = cosf(th),            s1 = sinf(th);

    const float ra0 = rot_alpha[0] * c0 - rot_alpha[2] * s0;
    const float ra1 = rot_alpha[1] * c1 - rot_alpha[3] * s1;
    const float ra2 = rot_alpha[2] * c0 + rot_alpha[0] * s0;
    const float ra3 = rot_alpha[3] * c1 + rot_alpha[1] * s1;
    const float rb0 = rot_beta[0] * c0 - rot_beta[2] * s0;
    const float rb1 = rot_beta[1] * c1 - rot_beta[3] * s1;
    const float rb2 = rot_beta[2] * c0 + rot_beta[0] * s0;
    const float rb3 = rot_beta[3] * c1 + rot_beta[1] * s1;

    const float invL = 1.0f / (float)LEN;
    float* q8 = g_Qv + l * 8;
    float* k8 = g_Kv + l * 8;
    #pragma unroll
    for (int s = 0; s < 4; ++s) {
        q8[s] = fmaf(z[s], attn_gamma[s],     attn_beta[s])     * invL;
        k8[s] = fmaf(z[s], attn_gamma[4 + s], attn_beta[4 + s]);
    }
    q8[4] = ra0; q8[5] = ra1; q8[6] = ra2; q8[7] = ra3;
    k8[4] = rb0; k8[5] = rb1; k8[6] = rb2; k8[7] = rb3;

    g_u[l] = u; g_hx[l] = hx; g_wsum[l] = ws;
}

// ---------------- K2: attention row-sum A[l] -> hh[l] -----------------------
// A[l] = sum_m relu(Qv[l].Kv[m])^2 ; hh[l] = silu(hx + A*wsum + bh0)
__global__ void k2_rowsum(const float* __restrict__ bh)
{
    const int l = blockIdx.x;
    const int tid = threadIdx.x;

    const float* q8 = g_Qv + l * 8;
    const float q0 = q8[0], q1 = q8[1], q2 = q8[2], q3 = q8[3];
    const float q4 = q8[4], q5 = q8[5], q6 = q8[6], q7 = q8[7];

    const float4* K4 = (const float4*)g_Kv;
    float acc = 0.0f;
    #pragma unroll
    for (int k = 0; k < LEN / 256; ++k) {
        int m = tid + k * 256;
        float4 ka = K4[m * 2];
        float4 kb = K4[m * 2 + 1];
        float d = q0 * ka.x + q1 * ka.y + q2 * ka.z + q3 * ka.w
                + q4 * kb.x + q5 * kb.y + q6 * kb.z + q7 * kb.w;
        d = fmaxf(d, 0.0f);
        acc = fmaf(d, d, acc);
    }
    #pragma unroll
    for (int off = 32; off; off >>= 1) acc += __shfl_down(acc, off, 64);

    __shared__ float red[4];
    if ((tid & 63) == 0) red[tid >> 6] = acc;
    __syncthreads();
    if (tid == 0) {
        float A = red[0] + red[1] + red[2] + red[3];
        g_hh[l] = siluf_(g_hx[l] + A * g_wsum[l] + bh[0]);
    }
}

// ---------------- K3: fused gate + output projection ------------------------
// out[l,b] = x[b,l] + u[l]*(hh[l]-x[b,l]);  y[b,p] = sum_l out[l,b]*Wlin[p,l] + blin[p]
// one block per p; wave w handles batches 8w..8w+7; lanes stride l.
__global__ void k3_output(
    const float* __restrict__ x,
    const float* __restrict__ Wlin, const float* __restrict__ blin,
    float* __restrict__ y)
{
    const int p    = blockIdx.x;
    const int tid  = threadIdx.x;
    const int wave = tid >> 6;
    const int lane = tid & 63;
    const int bbase = wave * 8;

    const float* wrow = Wlin + (size_t)p * LEN;
    float acc[8] = {0, 0, 0, 0, 0, 0, 0, 0};

    #pragma unroll 4
    for (int k = 0; k < LEN / 64; ++k) {
        const int l  = k * 64 + lane;
        const float wl  = wrow[l];
        const float ul  = g_u[l];
        const float hhl = g_hh[l];
        #pragma unroll
        for (int j = 0; j < 8; ++j) {
            float xv  = x[(size_t)(bbase + j) * LEN + l];
            float ov  = fmaf(ul, hhl - xv, xv);   // x + u*(hh - x)
            acc[j] = fmaf(ov, wl, acc[j]);
        }
    }
    #pragma unroll
    for (int j = 0; j < 8; ++j) {
        float v = acc[j];
        #pragma unroll
        for (int off = 32; off; off >>= 1) v += __shfl_down(v, off, 64);
        if (lane == 0) y[(size_t)(bbase + j) * PDIM + p] = v + blin[p];
    }
}

// ---------------- launch ----------------------------------------------------
extern "C" void kernel_launch(void* const* d_in, const int* in_sizes, int n_in,
                              void* d_out, int out_size, void* d_ws, size_t ws_size,
                              hipStream_t stream)
{
    const float* x          = (const float*)d_in[0];
    // d_in[1] = norm_w (dead: multiplies exact zero since E=1)
    const float* norm_b     = (const float*)d_in[2];
    const float* ema_delta  = (const float*)d_in[3];
    const float* ema_alpha  = (const float*)d_in[4];
    const float* ema_beta   = (const float*)d_in[5];
    const float* ema_gamma  = (const float*)d_in[6];
    const float* ema_omega  = (const float*)d_in[7];
    const float* Wv         = (const float*)d_in[8];
    const float* bv         = (const float*)d_in[9];
    const float* Wmx        = (const float*)d_in[10];
    const float* bmx        = (const float*)d_in[11];
    const float* Wh         = (const float*)d_in[12];
    const float* bh         = (const float*)d_in[13];
    const float* attn_gamma = (const float*)d_in[14];
    const float* attn_beta  = (const float*)d_in[15];
    const float* rot_alpha  = (const float*)d_in[16];
    const float* rot_beta   = (const float*)d_in[17];
    const float* Wlin       = (const float*)d_in[18];
    const float* blin       = (const float*)d_in[19];
    float* y = (float*)d_out;

    k1_precompute<<<LEN / 256, 256, 0, stream>>>(
        norm_b, ema_delta, ema_alpha, ema_beta, ema_gamma, ema_omega,
        Wv, bv, Wmx, bmx, Wh, attn_gamma, attn_beta, rot_alpha, rot_beta);

    k2_rowsum<<<LEN, 256, 0, stream>>>(bh);

    k3_output<<<PDIM, 256, 0, stream>>>(x, Wlin, blin, y);
}

// Round 5
// 123.473 us; speedup vs baseline: 1.2163x; 1.2163x over previous
//
#include <hip/hip_runtime.h>
#include <hip/hip_bf16.h>
#include <math.h>

// Shapes: L=2048, B=32, E=1, S=4, D=8, N=8, P=720
#define LEN 2048
#define BDIM 32
#define PDIM 720
#define CH 8                 // L-chunks for k3 split
#define CHLEN (LEN / CH)     // 256 l per chunk = 64 lanes x float4

// Scratch in device globals (NOT d_ws). Every region fully overwritten each
// call before any read (K1 writes Qv/Kv/u/hx/wsum; K2 writes hh; K3 writes
// all of g_part) => no cross-call state, re-poison-safe. No atomics, no
// memset on harness memory.
__device__ float g_Qv[LEN * 8];
__device__ float g_Kv[LEN * 8];
__device__ float g_u[LEN];
__device__ float g_hx[LEN];
__device__ float g_wsum[LEN];
__device__ float g_hh[LEN];
__device__ float g_part[CH * BDIM * PDIM];   // [ch][b][p]

__device__ __forceinline__ float sigmoidf_(float x) { return 1.0f / (1.0f + expf(-x)); }
__device__ __forceinline__ float siluf_(float x)    { return x / (1.0f + expf(-x)); }

// ---------------- K1: per-position precompute (E=1 collapse) ----------------
__global__ void k1_precompute(
    const float* __restrict__ norm_b,
    const float* __restrict__ ema_delta, const float* __restrict__ ema_alpha,
    const float* __restrict__ ema_beta,  const float* __restrict__ ema_gamma,
    const float* __restrict__ ema_omega,
    const float* __restrict__ Wv, const float* __restrict__ bv,
    const float* __restrict__ Wmx, const float* __restrict__ bmx,
    const float* __restrict__ Wh,
    const float* __restrict__ attn_gamma, const float* __restrict__ attn_beta,
    const float* __restrict__ rot_alpha,  const float* __restrict__ rot_beta)
{
    const int l = blockIdx.x * blockDim.x + threadIdx.x;
    if (l >= LEN) return;

    const float c = norm_b[0];
    const float res_e = c * ema_omega[0];

    // closed-form geometric prefix of the EMA long-conv (replaces the FFT)
    float conv = 0.0f;
    #pragma unroll
    for (int n = 0; n < 8; ++n) {
        float p  = sigmoidf_(ema_delta[n]);
        float s  = sigmoidf_(ema_alpha[n]);
        float om = p * s;            // 1-q in (0,1)
        float q  = 1.0f - om;
        float g  = p * ema_beta[n] * ema_gamma[n] * 0.35355339059327373f; // 1/sqrt(8)
        float qp = expf((float)(l + 1) * logf(q));
        conv += g * (1.0f - qp) / om;
    }
    conv *= c;

    const float mx = siluf_(conv + res_e);

    const float u  = sigmoidf_(fmaf(mx, Wmx[0], bmx[0]));
    float z[4];
    #pragma unroll
    for (int s = 0; s < 4; ++s) z[s] = siluf_(fmaf(mx, Wmx[1 + s], bmx[1 + s]));
    float r[8];
    #pragma unroll
    for (int d = 0; d < 8; ++d) r[d] = siluf_(fmaf(mx, Wmx[5 + d], bmx[5 + d]));
    const float hx = fmaf(mx, Wmx[13], bmx[13]);

    float ws = 0.0f;
    #pragma unroll
    for (int d = 0; d < 8; ++d) {
        float v = siluf_(fmaf(c, Wv[d], bv[d]));
        ws += v * r[d] * Wh[d];
    }

    // rotary: half=2, freq={1, exp(-log(1e4)/2)}
    const float f1 = expf(-logf(10000.0f) * 0.5f);
    const float c0 = cosf((float)l),      s0 = sinf((float)l);
    const float th = (float)l * f1;
    const float c1 = cosf(th),            s1 = sinf(th);

    const float ra0 = rot_alpha[0] * c0 - rot_alpha[2] * s0;
    const float ra1 = rot_alpha[1] * c1 - rot_alpha[3] * s1;
    const float ra2 = rot_alpha[2] * c0 + rot_alpha[0] * s0;
    const float ra3 = rot_alpha[3] * c1 + rot_alpha[1] * s1;
    const float rb0 = rot_beta[0] * c0 - rot_beta[2] * s0;
    const float rb1 = rot_beta[1] * c1 - rot_beta[3] * s1;
    const float rb2 = rot_beta[2] * c0 + rot_beta[0] * s0;
    const float rb3 = rot_beta[3] * c1 + rot_beta[1] * s1;

    const float invL = 1.0f / (float)LEN;
    float* q8 = g_Qv + l * 8;
    float* k8 = g_Kv + l * 8;
    #pragma unroll
    for (int s = 0; s < 4; ++s) {
        q8[s] = fmaf(z[s], attn_gamma[s],     attn_beta[s])     * invL;
        k8[s] = fmaf(z[s], attn_gamma[4 + s], attn_beta[4 + s]);
    }
    q8[4] = ra0; q8[5] = ra1; q8[6] = ra2; q8[7] = ra3;
    k8[4] = rb0; k8[5] = rb1; k8[6] = rb2; k8[7] = rb3;

    g_u[l] = u; g_hx[l] = hx; g_wsum[l] = ws;
}

// ---------------- K2: attention row-sum A[l] -> hh[l] -----------------------
__global__ void k2_rowsum(const float* __restrict__ bh)
{
    const int l = blockIdx.x;
    const int tid = threadIdx.x;

    const float* q8 = g_Qv + l * 8;
    const float q0 = q8[0], q1 = q8[1], q2 = q8[2], q3 = q8[3];
    const float q4 = q8[4], q5 = q8[5], q6 = q8[6], q7 = q8[7];

    const float4* K4 = (const float4*)g_Kv;
    float acc = 0.0f;
    #pragma unroll
    for (int k = 0; k < LEN / 256; ++k) {
        int m = tid + k * 256;
        float4 ka = K4[m * 2];
        float4 kb = K4[m * 2 + 1];
        float d = q0 * ka.x + q1 * ka.y + q2 * ka.z + q3 * ka.w
                + q4 * kb.x + q5 * kb.y + q6 * kb.z + q7 * kb.w;
        d = fmaxf(d, 0.0f);
        acc = fmaf(d, d, acc);
    }
    #pragma unroll
    for (int off = 32; off; off >>= 1) acc += __shfl_down(acc, off, 64);

    __shared__ float red[4];
    if ((tid & 63) == 0) red[tid >> 6] = acc;
    __syncthreads();
    if (tid == 0) {
        float A = red[0] + red[1] + red[2] + red[3];
        g_hh[l] = siluf_(g_hx[l] + A * g_wsum[l] + bh[0]);
    }
}

// ---------------- K3: split-L fused gate + output projection (partials) -----
// part[ch,b,p] = sum_{l in chunk} (x[b,l] + u[l]*(hh[l]-x[b,l])) * Wlin[p,l]
// grid (720 p, 8 chunks); block = 4 waves x 8 batches; float4 per lane along l.
__global__ void k3_partial(
    const float* __restrict__ x,
    const float* __restrict__ Wlin)
{
    const int p    = blockIdx.x;
    const int ch   = blockIdx.y;
    const int tid  = threadIdx.x;
    const int wave = tid >> 6;
    const int lane = tid & 63;
    const int bbase = wave * 8;
    const int idx4 = ch * (CHLEN / 4) + lane;   // float4 index along l

    // batch all loads first (one waitcnt), then compute
    const float4 wv = ((const float4*)Wlin)[(size_t)p * (LEN / 4) + idx4];
    const float4 uv = ((const float4*)g_u)[idx4];
    const float4 hv = ((const float4*)g_hh)[idx4];
    float4 xv[8];
    #pragma unroll
    for (int j = 0; j < 8; ++j)
        xv[j] = ((const float4*)(x + (size_t)(bbase + j) * LEN))[idx4];

    float acc[8];
    #pragma unroll
    for (int j = 0; j < 8; ++j) {
        float ox = fmaf(uv.x, hv.x - xv[j].x, xv[j].x);
        float oy = fmaf(uv.y, hv.y - xv[j].y, xv[j].y);
        float oz = fmaf(uv.z, hv.z - xv[j].z, xv[j].z);
        float ow = fmaf(uv.w, hv.w - xv[j].w, xv[j].w);
        acc[j] = fmaf(ox, wv.x, fmaf(oy, wv.y, fmaf(oz, wv.z, ow * wv.w)));
    }

    #pragma unroll
    for (int j = 0; j < 8; ++j) {
        float v = acc[j];
        #pragma unroll
        for (int off = 32; off; off >>= 1) v += __shfl_down(v, off, 64);
        if (lane == 0)
            g_part[(ch * BDIM + bbase + j) * PDIM + p] = v;
    }
}

// ---------------- K4: combine partials + bias -------------------------------
// y[b,p] = blin[p] + sum_ch part[ch,b,p]
__global__ void k4_combine(const float* __restrict__ blin, float* __restrict__ y)
{
    const int idx = blockIdx.x * blockDim.x + threadIdx.x;   // b*720 + p
    if (idx >= BDIM * PDIM) return;
    const int p = idx % PDIM;
    float v = blin[p];
    #pragma unroll
    for (int ch = 0; ch < CH; ++ch)
        v += g_part[ch * (BDIM * PDIM) + idx];
    y[idx] = v;
}

// ---------------- launch ----------------------------------------------------
extern "C" void kernel_launch(void* const* d_in, const int* in_sizes, int n_in,
                              void* d_out, int out_size, void* d_ws, size_t ws_size,
                              hipStream_t stream)
{
    const float* x          = (const float*)d_in[0];
    // d_in[1] = norm_w (dead: multiplies exact zero since E=1)
    const float* norm_b     = (const float*)d_in[2];
    const float* ema_delta  = (const float*)d_in[3];
    const float* ema_alpha  = (const float*)d_in[4];
    const float* ema_beta   = (const float*)d_in[5];
    const float* ema_gamma  = (const float*)d_in[6];
    const float* ema_omega  = (const float*)d_in[7];
    const float* Wv         = (const float*)d_in[8];
    const float* bv         = (const float*)d_in[9];
    const float* Wmx        = (const float*)d_in[10];
    const float* bmx        = (const float*)d_in[11];
    const float* Wh         = (const float*)d_in[12];
    const float* bh         = (const float*)d_in[13];
    const float* attn_gamma = (const float*)d_in[14];
    const float* attn_beta  = (const float*)d_in[15];
    const float* rot_alpha  = (const float*)d_in[16];
    const float* rot_beta   = (const float*)d_in[17];
    const float* Wlin       = (const float*)d_in[18];
    const float* blin       = (const float*)d_in[19];
    float* y = (float*)d_out;

    k1_precompute<<<LEN / 256, 256, 0, stream>>>(
        norm_b, ema_delta, ema_alpha, ema_beta, ema_gamma, ema_omega,
        Wv, bv, Wmx, bmx, Wh, attn_gamma, attn_beta, rot_alpha, rot_beta);

    k2_rowsum<<<LEN, 256, 0, stream>>>(bh);

    k3_partial<<<dim3(PDIM, CH), 256, 0, stream>>>(x, Wlin);

    k4_combine<<<(BDIM * PDIM + 255) / 256, 256, 0, stream>>>(blin, y);
}